// Round 10
// baseline (205.295 us; speedup 1.0000x reference)
//
#include <hip/hip_runtime.h>
#include <hip/hip_bf16.h>

// 3-layer GCN, fixed 24-node DAG, batch 65536.  Round-10 = round-7 all-MFMA
// 6-stage chain + X prefetch (round-8b) + builtin-only fast bf16 pack.
// Round-8's inline-asm v_cvt_pk_bf16_f32 produced absmax=inf (bad hi halves
// poisoning the static weight fragments) -> replaced with:
//   pack(lo,hi) = v_perm_b32(hi_bits+0x8000, lo_bits+0x8000, 0x07060302)
// i.e. round-half-up to bf16 + byte-select of the two high halves: 3 VALU ops
// per 2 values vs ~10 for software-RNE __float2bfloat16 (round-7's VALU tax).
// Ties round away-from-even (prob ~2^-16, 1 ulp) — negligible vs 1.47e-2 thr.
// Stage chain per pair (samples 2k,2k+1):
//   S1: T1 = X*W1            S2: G1 = relu(3*(Amix*T1 + b1))
//   S3: T2 = G1*(W3/3)       S4: G2 = relu(3*(Amix*T2 + b3))
//   S5: T3 = G2*(W2/3)       S6: out = mean(relu(3*(Amix*T3 + b2)))/3
// Amix x3 -> coeffs {1,3,sqrt3}; /3 folded into W3, W2, final scale (1/72).
// All LDS wave-private, no __syncthreads (same-wave DS ops in-order).
// Do NOT cap registers below (256,2): round-2's (256,4) spilled 650 MB.

typedef __attribute__((ext_vector_type(8))) short bf16x8;
typedef __attribute__((ext_vector_type(4))) float f32x4;

#define NBLK  1024
#define ITERS 8          // 2 samples (1 pair) per iter; 1024*4*16 = 65536

__device__ __forceinline__ unsigned short f2bf(float f) {
  __hip_bfloat16 h = __float2bfloat16(f);
  return __builtin_bit_cast(unsigned short, h);
}
// Fast pack: 2 f32 -> u32 of 2 bf16. Round-half-up + v_perm_b32 byte select.
__device__ __forceinline__ unsigned bpack(float lo, float hi) {
  unsigned ulo = __builtin_bit_cast(unsigned, lo) + 0x8000u;
  unsigned uhi = __builtin_bit_cast(unsigned, hi) + 0x8000u;
  // selector bytes (LSB..MSB) {2,3,6,7}: dst = { uhi[31:16], ulo[31:16] }
  return __builtin_amdgcn_perm(uhi, ulo, 0x07060302u);
}

union U16 { uint4 u; bf16x8 b; };

__device__ __forceinline__ bf16x8 pack8(const float v[8]) {
  U16 un;
  un.u.x = bpack(v[0], v[1]);
  un.u.y = bpack(v[2], v[3]);
  un.u.z = bpack(v[4], v[5]);
  un.u.w = bpack(v[6], v[7]);
  return un.b;
}
__device__ __forceinline__ uint2 pk4(f32x4 a) {
  uint2 r;
  r.x = bpack(a[0], a[1]);
  r.y = bpack(a[2], a[3]);
  return r;
}
__device__ __forceinline__ uint2 pk4r(f32x4 a) {
  const f32x4 z = {0.f, 0.f, 0.f, 0.f};
  return pk4(__builtin_elementwise_max(a, z));
}

__global__ __launch_bounds__(256, 2)
void gnn_kernel(const float* __restrict__ xg,  const float* __restrict__ w1g,
                const float* __restrict__ b1g, const float* __restrict__ w3g,
                const float* __restrict__ b3g, const float* __restrict__ w2g,
                const float* __restrict__ b2g, float* __restrict__ outg) {
  // wave-private LDS, pitch 72. bufA: [64][72] (T1 [ch][node], T2 [ch'][node'];
  // col 48 = bias b1/b3, cols 49..71 zero). bufB: [48][72] ([node][ch], G1/G2).
  // bufD: [16][72] (T3 [c][node], col 48 = b2).
  __shared__ __align__(16) unsigned short bufA_s[4][64 * 72];
  __shared__ __align__(16) unsigned short bufB_s[4][48 * 72];
  __shared__ __align__(16) unsigned short bufD_s[4][16 * 72];

  const int tid  = threadIdx.x;
  const int w    = tid >> 6;
  const int lane = tid & 63;
  const int l15  = lane & 15;
  const int g    = lane >> 4;
  unsigned short* bA = bufA_s[w];
  unsigned short* bB = bufB_s[w];
  unsigned short* bD = bufD_s[w];
  const int wgid = blockIdx.x * 4 + w;

  // ---- static fragments ----
  bf16x8 w1bf[4], w3f[4][2], w2f[2], amixB[3][2];
  {
    float v[8];
    #pragma unroll
    for (int nc = 0; nc < 4; ++nc) {
      #pragma unroll
      for (int j = 0; j < 8; ++j) { int k = 8 * g + j; v[j] = (k < 10) ? w1g[k * 64 + 16 * nc + l15] : 0.f; }
      w1bf[nc] = pack8(v);
      #pragma unroll
      for (int ks = 0; ks < 2; ++ks) {
        #pragma unroll
        for (int j = 0; j < 8; ++j) v[j] = w3g[(32 * ks + 8 * g + j) * 64 + 16 * nc + l15] * (1.f / 3.f);
        w3f[nc][ks] = pack8(v);
      }
    }
    #pragma unroll
    for (int ks = 0; ks < 2; ++ks) {
      #pragma unroll
      for (int j = 0; j < 8; ++j) {
        int k = 32 * ks + 8 * g + j;
        v[j] = (l15 < 10) ? w2g[k * 10 + l15] * (1.f / 3.f) : 0.f;
      }
      w2f[ks] = pack8(v);
    }
    // Amix_ext (x3): B-frag (n = node_out = 16*nn+l15, k = node_in; k==48 -> bias row)
    #pragma unroll
    for (int nn = 0; nn < 3; ++nn) {
      #pragma unroll
      for (int ks = 0; ks < 2; ++ks) {
        #pragma unroll
        for (int j = 0; j < 8; ++j) {
          const int k = 32 * ks + 8 * g + j, n = 16 * nn + l15;
          float c = 0.f;
          if (k == 48) c = 3.f;
          else if (k < 48 && (k / 24) == (n / 24)) {
            const int s = k % 24, t = n % 24;
            if (t < 2)      c = (s == t) ? 3.f : 0.f;
            else if (t < 4) c = (s == t) ? 1.f : ((s < 2) ? 1.7320508075688772f : 0.f);
            else { const int sa = (t & ~1) - 2; c = (s == t || s == sa || s == sa + 1) ? 1.f : 0.f; }
          }
          v[j] = c;
        }
        amixB[nn][ks] = pack8(v);
      }
    }
  }

  const unsigned short b1f = f2bf(b1g[lane]);   // lane = ch
  const unsigned short b3f = f2bf(b3g[lane]);

  // one-time LDS init: zero pads (cols 48..71) + b2 column
  {
    const uint4 z4 = {0, 0, 0, 0};
    *(uint4*)&bA[lane * 72 + 48] = z4;
    *(uint4*)&bA[lane * 72 + 56] = z4;
    *(uint4*)&bA[lane * 72 + 64] = z4;
    if (lane < 16) {
      *(uint4*)&bD[lane * 72 + 48] = z4;
      *(uint4*)&bD[lane * 72 + 56] = z4;
      *(uint4*)&bD[lane * 72 + 64] = z4;
      bD[lane * 72 + 48] = (lane < 10) ? f2bf(b2g[lane]) : (unsigned short)0;
    }
  }

  // X gather offsets: A-frag rows r = 16*mt + l15 (pair-space node)
  int xoff[3];
  #pragma unroll
  for (int mt = 0; mt < 3; ++mt) {
    const int r = 16 * mt + l15, sub = r / 24, n = r - 24 * sub;
    xoff[mt] = sub * 240 + n * 10;
  }

  // X prefetch registers: g==0 lanes hold k=0..7 (4 float2), g==1 lanes k=8..9
  float2 px[3][4];
  auto loadX = [&](const float* xb) {
    #pragma unroll
    for (int mt = 0; mt < 3; ++mt) {
      const float* xr = xb + xoff[mt];
      if (g == 0) {
        px[mt][0] = *(const float2*)(xr + 0);
        px[mt][1] = *(const float2*)(xr + 2);
        px[mt][2] = *(const float2*)(xr + 4);
        px[mt][3] = *(const float2*)(xr + 6);
      } else if (g == 1) {
        px[mt][0] = *(const float2*)(xr + 8);
      }
    }
  };
  loadX(xg + (long)(wgid * 16) * 240);          // preload pair 0

  const f32x4 zf = {0.f, 0.f, 0.f, 0.f};

  for (int it = 0; it < ITERS; ++it) {
    const int sp = wgid * 16 + it * 2;           // pair = samples sp, sp+1

    bA[lane * 72 + 48] = b1f;                    // bias-1 column for S2

    // ---------- consume prefetched X into A-frags, then prefetch next ----------
    bf16x8 ax[3];
    #pragma unroll
    for (int mt = 0; mt < 3; ++mt) {
      float v[8] = {0.f, 0.f, 0.f, 0.f, 0.f, 0.f, 0.f, 0.f};
      if (g == 0) {
        v[0] = px[mt][0].x; v[1] = px[mt][0].y; v[2] = px[mt][1].x; v[3] = px[mt][1].y;
        v[4] = px[mt][2].x; v[5] = px[mt][2].y; v[6] = px[mt][3].x; v[7] = px[mt][3].y;
      } else if (g == 1) {
        v[0] = px[mt][0].x; v[1] = px[mt][0].y;
      }
      ax[mt] = pack8(v);
    }
    if (it + 1 < ITERS) loadX(xg + (long)(sp + 2) * 240);   // hide HBM under S1..S6

    // ---------- S1: T1[node][ch] = X*W1 (K=10 pad 32); store bufA[ch][node] ----------
    f32x4 acc1[3][4];
    #pragma unroll
    for (int mt = 0; mt < 3; ++mt)
      #pragma unroll
      for (int nc = 0; nc < 4; ++nc)
        acc1[mt][nc] = __builtin_amdgcn_mfma_f32_16x16x32_bf16(ax[mt], w1bf[nc], zf, 0, 0, 0);
    #pragma unroll
    for (int mt = 0; mt < 3; ++mt)
      #pragma unroll
      for (int nc = 0; nc < 4; ++nc)
        *(uint2*)&bA[(16 * nc + l15) * 72 + 16 * mt + 4 * g] = pk4(acc1[mt][nc]);

    // ---------- S2: G1' = relu(3*(Amix*T1+b1)); A=bufA[ch][node], B=amixB ----------
    U16 a2[4][2];
    #pragma unroll
    for (int mi = 0; mi < 4; ++mi)
      #pragma unroll
      for (int ks = 0; ks < 2; ++ks)
        a2[mi][ks].u = *(const uint4*)&bA[(16 * mi + l15) * 72 + 32 * ks + 8 * g];
    bA[lane * 72 + 48] = b3f;                    // after S2 reads: bias-3 col for S4
    f32x4 acc2[4][3];
    #pragma unroll
    for (int mi = 0; mi < 4; ++mi)
      #pragma unroll
      for (int nn = 0; nn < 3; ++nn) {
        f32x4 t = __builtin_amdgcn_mfma_f32_16x16x32_bf16(a2[mi][0].b, amixB[nn][0], zf, 0, 0, 0);
        acc2[mi][nn] = __builtin_amdgcn_mfma_f32_16x16x32_bf16(a2[mi][1].b, amixB[nn][1], t, 0, 0, 0);
      }
    #pragma unroll
    for (int mi = 0; mi < 4; ++mi)
      #pragma unroll
      for (int nn = 0; nn < 3; ++nn)
        *(uint2*)&bB[(16 * nn + l15) * 72 + 16 * mi + 4 * g] = pk4r(acc2[mi][nn]);

    // ---------- S3: T2[node'][ch'] = G1'*(W3/3); store bufA[ch'][node'] ----------
    U16 a3[3][2];
    #pragma unroll
    for (int mt = 0; mt < 3; ++mt)
      #pragma unroll
      for (int ks = 0; ks < 2; ++ks)
        a3[mt][ks].u = *(const uint4*)&bB[(16 * mt + l15) * 72 + 32 * ks + 8 * g];
    f32x4 acc3[3][4];
    #pragma unroll
    for (int mt = 0; mt < 3; ++mt)
      #pragma unroll
      for (int nc = 0; nc < 4; ++nc) {
        f32x4 t = __builtin_amdgcn_mfma_f32_16x16x32_bf16(a3[mt][0].b, w3f[nc][0], zf, 0, 0, 0);
        acc3[mt][nc] = __builtin_amdgcn_mfma_f32_16x16x32_bf16(a3[mt][1].b, w3f[nc][1], t, 0, 0, 0);
      }
    #pragma unroll
    for (int mt = 0; mt < 3; ++mt)
      #pragma unroll
      for (int nc = 0; nc < 4; ++nc)
        *(uint2*)&bA[(16 * nc + l15) * 72 + 16 * mt + 4 * g] = pk4(acc3[mt][nc]);

    // ---------- S4: G2' = relu(3*(Amix*T2+b3)) ----------
    U16 a4[4][2];
    #pragma unroll
    for (int mi = 0; mi < 4; ++mi)
      #pragma unroll
      for (int ks = 0; ks < 2; ++ks)
        a4[mi][ks].u = *(const uint4*)&bA[(16 * mi + l15) * 72 + 32 * ks + 8 * g];
    f32x4 acc4[4][3];
    #pragma unroll
    for (int mi = 0; mi < 4; ++mi)
      #pragma unroll
      for (int nn = 0; nn < 3; ++nn) {
        f32x4 t = __builtin_amdgcn_mfma_f32_16x16x32_bf16(a4[mi][0].b, amixB[nn][0], zf, 0, 0, 0);
        acc4[mi][nn] = __builtin_amdgcn_mfma_f32_16x16x32_bf16(a4[mi][1].b, amixB[nn][1], t, 0, 0, 0);
      }
    #pragma unroll
    for (int mi = 0; mi < 4; ++mi)
      #pragma unroll
      for (int nn = 0; nn < 3; ++nn)
        *(uint2*)&bB[(16 * nn + l15) * 72 + 16 * mi + 4 * g] = pk4r(acc4[mi][nn]);

    // ---------- S5: T3[node''][c] = G2'*(W2/3); store bufD[c][node''] ----------
    U16 a5[3][2];
    #pragma unroll
    for (int mt = 0; mt < 3; ++mt)
      #pragma unroll
      for (int ks = 0; ks < 2; ++ks)
        a5[mt][ks].u = *(const uint4*)&bB[(16 * mt + l15) * 72 + 32 * ks + 8 * g];
    f32x4 acc5[3];
    #pragma unroll
    for (int mt = 0; mt < 3; ++mt) {
      f32x4 t = __builtin_amdgcn_mfma_f32_16x16x32_bf16(a5[mt][0].b, w2f[0], zf, 0, 0, 0);
      acc5[mt] = __builtin_amdgcn_mfma_f32_16x16x32_bf16(a5[mt][1].b, w2f[1], t, 0, 0, 0);
    }
    #pragma unroll
    for (int mt = 0; mt < 3; ++mt)
      *(uint2*)&bD[l15 * 72 + 16 * mt + 4 * g] = pk4(acc5[mt]);

    // ---------- S6: Amix*T3 + b2; rows=c (4g+r), cols=node (16nt+l15) ----------
    U16 a6[2];
    #pragma unroll
    for (int ks = 0; ks < 2; ++ks)
      a6[ks].u = *(const uint4*)&bD[l15 * 72 + 32 * ks + 8 * g];
    f32x4 acc6[3];
    #pragma unroll
    for (int nt = 0; nt < 3; ++nt) {
      f32x4 t = __builtin_amdgcn_mfma_f32_16x16x32_bf16(a6[0].b, amixB[nt][0], zf, 0, 0, 0);
      acc6[nt] = __builtin_amdgcn_mfma_f32_16x16x32_bf16(a6[1].b, amixB[nt][1], t, 0, 0, 0);
    }

    // ---------- epilogue: relu, mean over nodes (sample split at node 24) ----------
    {
      f32x4 v0 = __builtin_elementwise_max(acc6[0], zf);
      f32x4 v1 = __builtin_elementwise_max(acc6[1], zf);
      f32x4 v2 = __builtin_elementwise_max(acc6[2], zf);
      f32x4 sum0 = v0, sum1 = v2;
      if (l15 < 8) sum0 += v1; else sum1 += v1;
      #pragma unroll
      for (int d = 1; d < 16; d <<= 1) {
        #pragma unroll
        for (int r = 0; r < 4; ++r) {
          sum0[r] += __shfl_xor(sum0[r], d);
          sum1[r] += __shfl_xor(sum1[r], d);
        }
      }
      if (l15 < 2) {
        const f32x4 s = (l15 == 0) ? sum0 : sum1;
        const float sc = 1.f / 72.f;              // mean/24 and the /3 Amix scale
        const long  so = (long)(sp + l15) * 10;
        if (g < 3) { float2 t0 = {s[0] * sc, s[1] * sc}; *(float2*)&outg[so + 4 * g] = t0; }
        if (g < 2) { float2 t1 = {s[2] * sc, s[3] * sc}; *(float2*)&outg[so + 4 * g + 2] = t1; }
      }
    }
  }
}

extern "C" void kernel_launch(void* const* d_in, const int* in_sizes, int n_in,
                              void* d_out, int out_size, void* d_ws, size_t ws_size,
                              hipStream_t stream) {
  (void)in_sizes; (void)n_in; (void)d_ws; (void)ws_size; (void)out_size;
  const float* x  = (const float*)d_in[0];
  const float* W1 = (const float*)d_in[1];
  const float* b1 = (const float*)d_in[2];
  const float* W3 = (const float*)d_in[3];
  const float* b3 = (const float*)d_in[4];
  const float* W2 = (const float*)d_in[5];
  const float* b2 = (const float*)d_in[6];
  // d_in[7] = edge_index: fixed compile-time DAG; Amix coefficients hard-coded.
  float* out = (float*)d_out;
  hipLaunchKernelGGL(gnn_kernel, dim3(NBLK), dim3(256), 0, stream,
                     x, W1, b1, W3, b3, W2, b2, out);
}